// Round 14
// baseline (682.201 us; speedup 1.0000x reference)
//
#include <hip/hip_runtime.h>
#include <hip/hip_bf16.h>

#define B_SZ 256
#define D_SZ 256
#define M_SZ 65536
#define C_SZ 1000
#define TEMP 0.05f
#define EPSF 1e-6f

#define CPB 2                    // classes per csum block
#define NBLK_CSUM (C_SZ / CPB)   // 500 blocks
#define LCAP 512                 // member-list capacity

// DIAGNOSTIC ROUND: internal repeats to surface per-kernel counters in top-5.
#define REPS_CSUM 12
#define REPS_LOSS 64

// packed bf16 fct layout: ushort index (d>>2)*(C_SZ*4) + c*4 + (d&3)

// ---- ws layout (bytes) ----
#define OFF_FCT   0          // ushort[D_SZ*C_SZ] = 512,000 B (packed bf16)
#define OFF_NUMS  512000     // int[C_SZ]
#define OFF_ACC   516000     // float[2]
#define OFF_LCNT  516008     // int[1] loss ticket

static __device__ __forceinline__ unsigned short f2bf(float f) {
    __hip_bfloat16 h = __float2bfloat16(f);   // RNE
    return *reinterpret_cast<unsigned short*>(&h);
}
#define BFLO(u) __uint_as_float(((unsigned)(u)) << 16)
#define BFHI(u) __uint_as_float(((unsigned)(u)) & 0xffff0000u)

__launch_bounds__(1024)
__global__ void k_csum(const float* __restrict__ features,
                       const int* __restrict__ labels,
                       unsigned short* __restrict__ fct, int* __restrict__ nums,
                       float* __restrict__ acc, int* __restrict__ lcnt,
                       int reps) {
    __shared__ int list[CPB][LCAP];
    __shared__ int lcur[CPB];
    __shared__ float4 red[CPB][8][64];
    int t = threadIdx.x, b = blockIdx.x;
    int c0 = b * CPB;

    if (b == 0 && t == 0) { acc[0] = 0.f; acc[1] = 0.f; lcnt[0] = 0; }

    for (int rep = 0; rep < reps; ++rep) {
        if (t < CPB) lcur[t] = 0;
        __syncthreads();

        // ---- phase 1: label scan ----
        const int4* L4 = (const int4*)labels;
        #pragma unroll
        for (int k = 0; k < M_SZ / 4 / 1024; ++k) {
            int idx = k * 1024 + t;
            int4 l4 = L4[idx];
            int m0 = idx * 4;
            unsigned d;
            d = (unsigned)(l4.x - c0); if (d < CPB) list[d][atomicAdd(&lcur[d], 1)] = m0 + 0;
            d = (unsigned)(l4.y - c0); if (d < CPB) list[d][atomicAdd(&lcur[d], 1)] = m0 + 1;
            d = (unsigned)(l4.z - c0); if (d < CPB) list[d][atomicAdd(&lcur[d], 1)] = m0 + 2;
            d = (unsigned)(l4.w - c0); if (d < CPB) list[d][atomicAdd(&lcur[d], 1)] = m0 + 3;
        }
        __syncthreads();

        // ---- phase 2: float4 gather ----
        int g = t >> 9;
        int tt = t & 511;
        int s = tt >> 6;
        int lane = tt & 63;
        int c = c0 + g;
        int n = lcur[g];
        const int* ml = list[g];
        float4 a = make_float4(0.f, 0.f, 0.f, 0.f);
        #pragma unroll 4
        for (int i = s; i < n; i += 8) {
            float4 v = *(const float4*)&features[(size_t)ml[i] * D_SZ + lane * 4];
            a.x += v.x; a.y += v.y; a.z += v.z; a.w += v.w;
        }
        red[g][s][lane] = a;
        __syncthreads();
        if (s == 0) {
            float4 z = make_float4(0.f, 0.f, 0.f, 0.f);
            #pragma unroll
            for (int q = 0; q < 8; ++q) {
                float4 r = red[g][q][lane];
                z.x += r.x; z.y += r.y; z.z += r.z; z.w += r.w;
            }
            float scale = 1.0f / (TEMP * (float)(n > 0 ? n : 1));
            ushort4 o;
            o.x = f2bf(z.x * scale); o.y = f2bf(z.y * scale);
            o.z = f2bf(z.z * scale); o.w = f2bf(z.w * scale);
            *(ushort4*)&fct[(size_t)lane * (C_SZ * 4) + c * 4] = o;
            if (lane == 0) nums[c] = n;
        }
        __syncthreads();   // protect list/red/lcur before next rep
    }
}

__launch_bounds__(1024)
__global__ void k_loss(const float* __restrict__ feat,
                       const unsigned short* __restrict__ fct,
                       const int* __restrict__ nums,
                       const float* __restrict__ soft,
                       const int* __restrict__ indexes,
                       const int* __restrict__ labels,
                       const int* __restrict__ bil,
                       const int* __restrict__ cur_epoch,
                       float* __restrict__ acc, int* __restrict__ lcnt,
                       float* __restrict__ out, int reps) {
    __shared__ float xs0[D_SZ], xs1[D_SZ];
    __shared__ float pa[4][256][9];
    __shared__ float wred[16], wred2[16];
    __shared__ float bc0, bc1;
    __shared__ int tgt0, tgt1, sr0, sr1;

    int t = threadIdx.x;
    int lane = t & 63, wid = t >> 6;
    int r0 = blockIdx.x * 2;

    if (t == 0) {
        tgt0 = labels[indexes[r0]];
        tgt1 = labels[indexes[r0 + 1]];
        sr0 = bil[r0];
        sr1 = bil[r0 + 1];
    }

    float e0[4], e1[4];
    float inv0 = 0.f, inv1 = 0.f;

    for (int rep = 0; rep < reps; ++rep) {
        // ---- normalize rows 2r,2r+1 ----
        float v = (t < 512) ? feat[(size_t)r0 * D_SZ + t] : 0.f;
        float s = v * v;
        #pragma unroll
        for (int o = 32; o; o >>= 1) s += __shfl_down(s, o);
        if (lane == 0) wred[wid] = s;
        __syncthreads();
        if (t == 0) {
            bc0 = fmaxf(sqrtf(wred[0] + wred[1] + wred[2] + wred[3]), 1e-12f);
            bc1 = fmaxf(sqrtf(wred[4] + wred[5] + wred[6] + wred[7]), 1e-12f);
        }
        __syncthreads();
        if (t < 256) xs0[t] = v / bc0;
        else if (t < 512) xs1[t - 256] = v / bc1;
        __syncthreads();

        // ---- phase B: partial sims ----
        int q = t >> 8, tt = t & 255;
        int c0 = 4 * tt;
        float b00 = 0.f, b01 = 0.f, b02 = 0.f, b03 = 0.f;
        float b10 = 0.f, b11 = 0.f, b12 = 0.f, b13 = 0.f;
        if (tt < 250) {
            int jb = q * 16;
            #pragma unroll 4
            for (int j = jb; j < jb + 16; ++j) {
                const unsigned short* base = fct + (size_t)j * (C_SZ * 4) + c0 * 4;
                int4 u0 = *(const int4*)base;
                int4 u1 = *(const int4*)(base + 8);
                float4 x0 = *(const float4*)&xs0[4 * j];
                float4 x1 = *(const float4*)&xs1[4 * j];
                float f0, f1, f2, f3;
                f0 = BFLO(u0.x); f1 = BFHI(u0.x); f2 = BFLO(u0.y); f3 = BFHI(u0.y);
                b00 = fmaf(x0.x, f0, b00); b00 = fmaf(x0.y, f1, b00);
                b00 = fmaf(x0.z, f2, b00); b00 = fmaf(x0.w, f3, b00);
                b10 = fmaf(x1.x, f0, b10); b10 = fmaf(x1.y, f1, b10);
                b10 = fmaf(x1.z, f2, b10); b10 = fmaf(x1.w, f3, b10);
                f0 = BFLO(u0.z); f1 = BFHI(u0.z); f2 = BFLO(u0.w); f3 = BFHI(u0.w);
                b01 = fmaf(x0.x, f0, b01); b01 = fmaf(x0.y, f1, b01);
                b01 = fmaf(x0.z, f2, b01); b01 = fmaf(x0.w, f3, b01);
                b11 = fmaf(x1.x, f0, b11); b11 = fmaf(x1.y, f1, b11);
                b11 = fmaf(x1.z, f2, b11); b11 = fmaf(x1.w, f3, b11);
                f0 = BFLO(u1.x); f1 = BFHI(u1.x); f2 = BFLO(u1.y); f3 = BFHI(u1.y);
                b02 = fmaf(x0.x, f0, b02); b02 = fmaf(x0.y, f1, b02);
                b02 = fmaf(x0.z, f2, b02); b02 = fmaf(x0.w, f3, b02);
                b12 = fmaf(x1.x, f0, b12); b12 = fmaf(x1.y, f1, b12);
                b12 = fmaf(x1.z, f2, b12); b12 = fmaf(x1.w, f3, b12);
                f0 = BFLO(u1.z); f1 = BFHI(u1.z); f2 = BFLO(u1.w); f3 = BFHI(u1.w);
                b03 = fmaf(x0.x, f0, b03); b03 = fmaf(x0.y, f1, b03);
                b03 = fmaf(x0.z, f2, b03); b03 = fmaf(x0.w, f3, b03);
                b13 = fmaf(x1.x, f0, b13); b13 = fmaf(x1.y, f1, b13);
                b13 = fmaf(x1.z, f2, b13); b13 = fmaf(x1.w, f3, b13);
            }
        }
        pa[q][tt][0] = b00; pa[q][tt][1] = b10;
        pa[q][tt][2] = b01; pa[q][tt][3] = b11;
        pa[q][tt][4] = b02; pa[q][tt][5] = b12;
        pa[q][tt][6] = b03; pa[q][tt][7] = b13;
        __syncthreads();

        // ---- phase C: reduce + masked exp ----
        float s0 = 0.f, s1 = 0.f;
        e0[0] = e0[1] = e0[2] = e0[3] = 0.f;
        e1[0] = e1[1] = e1[2] = e1[3] = 0.f;
        if (t < 250) {
            int4 nm = *(const int4*)&nums[4 * t];
            #pragma unroll
            for (int k = 0; k < 4; ++k) {
                float a0 = (pa[0][t][2 * k] + pa[1][t][2 * k]) +
                           (pa[2][t][2 * k] + pa[3][t][2 * k]);
                float a1 = (pa[0][t][2 * k + 1] + pa[1][t][2 * k + 1]) +
                           (pa[2][t][2 * k + 1] + pa[3][t][2 * k + 1]);
                int nk = (k == 0) ? nm.x : (k == 1) ? nm.y : (k == 2) ? nm.z : nm.w;
                float mk = (nk > 0) ? 1.f : 0.f;
                e0[k] = mk * __expf(a0);
                e1[k] = mk * __expf(a1);
                s0 += e0[k];
                s1 += e1[k];
            }
        }
        #pragma unroll
        for (int o = 32; o; o >>= 1) {
            s0 += __shfl_down(s0, o);
            s1 += __shfl_down(s1, o);
        }
        if (lane == 0) { wred[wid] = s0; wred2[wid] = s1; }
        __syncthreads();
        if (t == 0) {
            float z0 = 0.f, z1 = 0.f;
            #pragma unroll
            for (int i = 0; i < 16; ++i) { z0 += wred[i]; z1 += wred2[i]; }
            bc0 = z0; bc1 = z1;
        }
        __syncthreads();
        inv0 = 1.0f / (bc0 + EPSF);
        inv1 = 1.0f / (bc1 + EPSF);
        // keep results live so reps can't be CSE'd/hoisted (rule #17)
        asm volatile("" :: "v"(inv0), "v"(inv1), "v"(e0[0]), "v"(e1[0]));
        __syncthreads();   // protect bc0/bc1 before next rep's wred writes
    }

    // ---- loss partials (once) ----
    float p1 = 0.f, p2 = 0.f;
    if (t < 250) {
        int c0b = 4 * t;
        float4 sp0 = *(const float4*)&soft[(size_t)sr0 * C_SZ + c0b];
        float4 sp1 = *(const float4*)&soft[(size_t)sr1 * C_SZ + c0b];
        #pragma unroll
        for (int k = 0; k < 4; ++k) {
            float w0 = (k == 0) ? sp0.x : (k == 1) ? sp0.y : (k == 2) ? sp0.z : sp0.w;
            float w1 = (k == 0) ? sp1.x : (k == 1) ? sp1.y : (k == 2) ? sp1.z : sp1.w;
            float lp0 = __logf(e0[k] * inv0 + EPSF);
            float lp1 = __logf(e1[k] * inv1 + EPSF);
            p2 -= w0 * lp0 + w1 * lp1;
            if (c0b + k == tgt0) p1 -= lp0;
            if (c0b + k == tgt1) p1 -= lp1;
        }
    }
    #pragma unroll
    for (int o = 32; o; o >>= 1) {
        p1 += __shfl_down(p1, o);
        p2 += __shfl_down(p2, o);
    }
    __syncthreads();
    if (lane == 0) { wred[wid] = p1; wred2[wid] = p2; }
    __syncthreads();
    if (t == 0) {
        float z1 = 0.f, z2 = 0.f;
        #pragma unroll
        for (int i = 0; i < 16; ++i) { z1 += wred[i]; z2 += wred2[i]; }
        atomicAdd(&acc[0], z1);
        atomicAdd(&acc[1], z2);
        __threadfence();
        int done = atomicAdd(lcnt, 1);
        if (done == (int)gridDim.x - 1) {
            float l1 = atomicAdd(&acc[0], 0.f) / (float)B_SZ;
            float l2 = atomicAdd(&acc[1], 0.f) / (float)B_SZ;
            out[0] = (cur_epoch[0] == 0) ? l1 : 0.5f * (l1 + l2);
        }
    }
}

extern "C" void kernel_launch(void* const* d_in, const int* in_sizes, int n_in,
                              void* d_out, int out_size, void* d_ws, size_t ws_size,
                              hipStream_t stream) {
    const float* feat     = (const float*)d_in[0];
    const float* features = (const float*)d_in[1];
    const float* soft     = (const float*)d_in[2];
    const int* indexes    = (const int*)d_in[3];
    const int* labels     = (const int*)d_in[4];
    const int* bil        = (const int*)d_in[5];
    const int* cur_epoch  = (const int*)d_in[6];

    char* ws = (char*)d_ws;
    unsigned short* fct = (unsigned short*)(ws + OFF_FCT);
    int* nums    = (int*)(ws + OFF_NUMS);
    float* acc   = (float*)(ws + OFF_ACC);
    int* lcnt    = (int*)(ws + OFF_LCNT);

    k_csum<<<NBLK_CSUM, 1024, 0, stream>>>(features, labels, fct, nums, acc, lcnt,
                                           REPS_CSUM);
    k_loss<<<B_SZ / 2, 1024, 0, stream>>>(feat, fct, nums, soft, indexes, labels,
                                          bil, cur_epoch, acc, lcnt, (float*)d_out,
                                          REPS_LOSS);
}

// Round 15
// 54.372 us; speedup vs baseline: 12.5470x; 12.5470x over previous
//
#include <hip/hip_runtime.h>

#define B_SZ 256
#define D_SZ 256
#define M_SZ 65536
#define C_SZ 1000
#define TEMP 0.05f
#define EPSF 1e-6f

#define CPB 2                    // classes per csum block
#define NBLK_CSUM (C_SZ / CPB)   // 500 blocks
#define LCAP 512                 // member-list capacity (lambda=65.5)

// packed fp32 fct layout: float index (d>>2)*(C_SZ*4) + c*4 + (d&3)
// -> for dim-quad j, class c: 4 contiguous floats (one float4)

// ---- ws layout (bytes) ----
#define OFF_FCT   0          // float[D_SZ*C_SZ] = 1,024,000 B (packed fp32)
#define OFF_NUMS  1024000    // int[C_SZ]
#define OFF_ACC   1028000    // float[2]
#define OFF_LCNT  1028008    // int[1] loss ticket

// Self-sufficient classsum: block b owns classes 2b, 2b+1.
// Phase 1: scan all labels (int4, L2-broadcast), append to per-class LDS lists.
// Phase 2: 8 row-streams x 64 lanes per class, unroll 8 -> 8 HBM chains in
//          flight (csum is latency-bound per R14 diagnostic).
__launch_bounds__(1024)
__global__ void k_csum(const float* __restrict__ features,
                       const int* __restrict__ labels,
                       float* __restrict__ fct, int* __restrict__ nums,
                       float* __restrict__ acc, int* __restrict__ lcnt) {
    __shared__ int list[CPB][LCAP];
    __shared__ int lcur[CPB];
    __shared__ float4 red[CPB][8][64];   // 16 KB
    int t = threadIdx.x, b = blockIdx.x;
    int c0 = b * CPB;

    if (t < CPB) lcur[t] = 0;
    if (b == 0 && t == 0) { acc[0] = 0.f; acc[1] = 0.f; lcnt[0] = 0; }
    __syncthreads();

    // ---- phase 1: label scan ----
    const int4* L4 = (const int4*)labels;
    #pragma unroll
    for (int k = 0; k < M_SZ / 4 / 1024; ++k) {   // 16 iters
        int idx = k * 1024 + t;
        int4 l4 = L4[idx];
        int m0 = idx * 4;
        unsigned d;
        d = (unsigned)(l4.x - c0); if (d < CPB) list[d][atomicAdd(&lcur[d], 1)] = m0 + 0;
        d = (unsigned)(l4.y - c0); if (d < CPB) list[d][atomicAdd(&lcur[d], 1)] = m0 + 1;
        d = (unsigned)(l4.z - c0); if (d < CPB) list[d][atomicAdd(&lcur[d], 1)] = m0 + 2;
        d = (unsigned)(l4.w - c0); if (d < CPB) list[d][atomicAdd(&lcur[d], 1)] = m0 + 3;
    }
    __syncthreads();

    // ---- phase 2: float4 gather, 8 chains in flight ----
    int g = t >> 9;          // class subgroup (0/1)
    int tt = t & 511;
    int s = tt >> 6;         // row stream 0..7
    int lane = tt & 63;      // 16B slice of the row
    int c = c0 + g;
    int n = lcur[g];
    const int* ml = list[g];
    float4 a = make_float4(0.f, 0.f, 0.f, 0.f);
    #pragma unroll 8
    for (int i = s; i < n; i += 8) {
        float4 v = *(const float4*)&features[(size_t)ml[i] * D_SZ + lane * 4];
        a.x += v.x; a.y += v.y; a.z += v.z; a.w += v.w;
    }
    red[g][s][lane] = a;
    __syncthreads();
    if (s == 0) {
        float4 z = make_float4(0.f, 0.f, 0.f, 0.f);
        #pragma unroll
        for (int q = 0; q < 8; ++q) {
            float4 r = red[g][q][lane];
            z.x += r.x; z.y += r.y; z.z += r.z; z.w += r.w;
        }
        float scale = 1.0f / (TEMP * (float)(n > 0 ? n : 1));
        z.x *= scale; z.y *= scale; z.z *= scale; z.w *= scale;
        // packed: dims 4*lane..4*lane+3 for class c
        *(float4*)&fct[(size_t)lane * (C_SZ * 4) + c * 4] = z;
        if (lane == 0) nums[c] = n;
    }
}

// 256 blocks x 1024 thr, ONE row per block (R14 diag: loss is VALU-bound at
// 23.7% occupancy -> use all CUs, and fp32 fct kills the 256 unpack ops).
// Thread t: dim-chunk q = t>>8 (64 dims), class-quad 4*(t&255).
__launch_bounds__(1024)
__global__ void k_loss(const float* __restrict__ feat,
                       const float* __restrict__ fct,
                       const int* __restrict__ nums,
                       const float* __restrict__ soft,
                       const int* __restrict__ indexes,
                       const int* __restrict__ labels,
                       const int* __restrict__ bil,
                       const int* __restrict__ cur_epoch,
                       float* __restrict__ acc, int* __restrict__ lcnt,
                       float* __restrict__ out) {
    __shared__ float xs[D_SZ];
    __shared__ float pa[4][256][5];   // [q][tt][cls], pad 5
    __shared__ float wred[16], wred2[16];
    __shared__ float bc0;
    __shared__ int tgt0, sr0;

    int t = threadIdx.x;
    int lane = t & 63, wid = t >> 6;
    int r = blockIdx.x;

    if (t == 0) {
        tgt0 = labels[indexes[r]];
        sr0 = bil[r];
    }

    // ---- normalize row r ----
    float v = (t < D_SZ) ? feat[(size_t)r * D_SZ + t] : 0.f;
    float s = v * v;
    #pragma unroll
    for (int o = 32; o; o >>= 1) s += __shfl_down(s, o);
    if (lane == 0) wred[wid] = s;   // waves 0-3 hold the row
    __syncthreads();
    if (t == 0)
        bc0 = fmaxf(sqrtf(wred[0] + wred[1] + wred[2] + wred[3]), 1e-12f);
    __syncthreads();
    if (t < D_SZ) xs[t] = v / bc0;
    __syncthreads();

    // ---- phase B: partial sims for 4 classes over my 64 dims ----
    int q = t >> 8, tt = t & 255;
    int c0 = 4 * tt;
    float b0 = 0.f, b1 = 0.f, b2 = 0.f, b3 = 0.f;
    if (tt < 250) {
        int jb = q * 16;
        #pragma unroll 4
        for (int j = jb; j < jb + 16; ++j) {
            const float* base = fct + (size_t)j * (C_SZ * 4) + c0 * 4;
            float4 f0 = *(const float4*)(base);       // class c0
            float4 f1 = *(const float4*)(base + 4);   // class c0+1
            float4 f2 = *(const float4*)(base + 8);   // class c0+2
            float4 f3 = *(const float4*)(base + 12);  // class c0+3
            float4 x = *(const float4*)&xs[4 * j];    // ds_read_b128
            b0 = fmaf(x.x, f0.x, b0); b0 = fmaf(x.y, f0.y, b0);
            b0 = fmaf(x.z, f0.z, b0); b0 = fmaf(x.w, f0.w, b0);
            b1 = fmaf(x.x, f1.x, b1); b1 = fmaf(x.y, f1.y, b1);
            b1 = fmaf(x.z, f1.z, b1); b1 = fmaf(x.w, f1.w, b1);
            b2 = fmaf(x.x, f2.x, b2); b2 = fmaf(x.y, f2.y, b2);
            b2 = fmaf(x.z, f2.z, b2); b2 = fmaf(x.w, f2.w, b2);
            b3 = fmaf(x.x, f3.x, b3); b3 = fmaf(x.y, f3.y, b3);
            b3 = fmaf(x.z, f3.z, b3); b3 = fmaf(x.w, f3.w, b3);
        }
    }
    pa[q][tt][0] = b0; pa[q][tt][1] = b1;
    pa[q][tt][2] = b2; pa[q][tt][3] = b3;
    __syncthreads();

    // ---- phase C: reduce partials, masked exp ----
    float e0[4] = {0.f, 0.f, 0.f, 0.f};
    float s0 = 0.f;
    if (t < 250) {
        int4 nm = *(const int4*)&nums[4 * t];
        #pragma unroll
        for (int k = 0; k < 4; ++k) {
            float a0 = (pa[0][t][k] + pa[1][t][k]) + (pa[2][t][k] + pa[3][t][k]);
            int nk = (k == 0) ? nm.x : (k == 1) ? nm.y : (k == 2) ? nm.z : nm.w;
            float mk = (nk > 0) ? 1.f : 0.f;
            e0[k] = mk * __expf(a0);
            s0 += e0[k];
        }
    }
    #pragma unroll
    for (int o = 32; o; o >>= 1) s0 += __shfl_down(s0, o);
    if (lane == 0) wred[wid] = s0;
    __syncthreads();
    if (t == 0) {
        float z0 = 0.f;
        #pragma unroll
        for (int i = 0; i < 16; ++i) z0 += wred[i];
        bc0 = z0;
    }
    __syncthreads();
    float inv0 = 1.0f / (bc0 + EPSF);

    // ---- loss partials ----
    float p1 = 0.f, p2 = 0.f;
    if (t < 250) {
        int c0b = 4 * t;
        float4 sp0 = *(const float4*)&soft[(size_t)sr0 * C_SZ + c0b];
        #pragma unroll
        for (int k = 0; k < 4; ++k) {
            float w0 = (k == 0) ? sp0.x : (k == 1) ? sp0.y : (k == 2) ? sp0.z : sp0.w;
            float lp0 = __logf(e0[k] * inv0 + EPSF);
            p2 -= w0 * lp0;
            if (c0b + k == tgt0) p1 -= lp0;
        }
    }
    #pragma unroll
    for (int o = 32; o; o >>= 1) {
        p1 += __shfl_down(p1, o);
        p2 += __shfl_down(p2, o);
    }
    __syncthreads();
    if (lane == 0) { wred[wid] = p1; wred2[wid] = p2; }
    __syncthreads();
    if (t == 0) {
        float z1 = 0.f, z2 = 0.f;
        #pragma unroll
        for (int i = 0; i < 16; ++i) { z1 += wred[i]; z2 += wred2[i]; }
        atomicAdd(&acc[0], z1);
        atomicAdd(&acc[1], z2);
        __threadfence();
        int done = atomicAdd(lcnt, 1);
        if (done == (int)gridDim.x - 1) {
            float l1 = atomicAdd(&acc[0], 0.f) / (float)B_SZ;
            float l2 = atomicAdd(&acc[1], 0.f) / (float)B_SZ;
            out[0] = (cur_epoch[0] == 0) ? l1 : 0.5f * (l1 + l2);
        }
    }
}

extern "C" void kernel_launch(void* const* d_in, const int* in_sizes, int n_in,
                              void* d_out, int out_size, void* d_ws, size_t ws_size,
                              hipStream_t stream) {
    const float* feat     = (const float*)d_in[0];
    const float* features = (const float*)d_in[1];
    const float* soft     = (const float*)d_in[2];
    const int* indexes    = (const int*)d_in[3];
    const int* labels     = (const int*)d_in[4];
    const int* bil        = (const int*)d_in[5];
    const int* cur_epoch  = (const int*)d_in[6];

    char* ws = (char*)d_ws;
    float* fct   = (float*)(ws + OFF_FCT);
    int* nums    = (int*)(ws + OFF_NUMS);
    float* acc   = (float*)(ws + OFF_ACC);
    int* lcnt    = (int*)(ws + OFF_LCNT);

    k_csum<<<NBLK_CSUM, 1024, 0, stream>>>(features, labels, fct, nums, acc, lcnt);
    k_loss<<<B_SZ, 1024, 0, stream>>>(feat, fct, nums, soft, indexes, labels,
                                      bil, cur_epoch, acc, lcnt, (float*)d_out);
}

// Round 16
// 43.989 us; speedup vs baseline: 15.5086x; 1.2360x over previous
//
#include <hip/hip_runtime.h>
#include <hip/hip_bf16.h>

#define B_SZ 256
#define D_SZ 256
#define M_SZ 65536
#define C_SZ 1000
#define TEMP 0.05f
#define EPSF 1e-6f

#define CPB 2                    // classes per csum block
#define NBLK_CSUM (C_SZ / CPB)   // 500 blocks
#define LCAP 512                 // member-list capacity (lambda=65.5)

// packed bf16 fct layout: ushort index (d>>2)*(C_SZ*4) + c*4 + (d&3)

// ---- ws layout (bytes) ----
#define OFF_FCT   0          // ushort[D_SZ*C_SZ] = 512,000 B (packed bf16)
#define OFF_NUMS  512000     // int[C_SZ]
#define OFF_ACC   516000     // float[2]
#define OFF_LCNT  516008     // int[1] loss ticket

static __device__ __forceinline__ unsigned short f2bf(float f) {
    __hip_bfloat16 h = __float2bfloat16(f);   // RNE
    return *reinterpret_cast<unsigned short*>(&h);
}
#define BFLO(u) __uint_as_float(((unsigned)(u)) << 16)
#define BFHI(u) __uint_as_float(((unsigned)(u)) & 0xffff0000u)

// Self-sufficient classsum — EXACT R13 version (best measured).
__launch_bounds__(1024)
__global__ void k_csum(const float* __restrict__ features,
                       const int* __restrict__ labels,
                       unsigned short* __restrict__ fct, int* __restrict__ nums,
                       float* __restrict__ acc, int* __restrict__ lcnt) {
    __shared__ int list[CPB][LCAP];
    __shared__ int lcur[CPB];
    __shared__ float4 red[CPB][8][64];   // 16 KB
    int t = threadIdx.x, b = blockIdx.x;
    int c0 = b * CPB;

    if (t < CPB) lcur[t] = 0;
    if (b == 0 && t == 0) { acc[0] = 0.f; acc[1] = 0.f; lcnt[0] = 0; }
    __syncthreads();

    // ---- phase 1: label scan ----
    const int4* L4 = (const int4*)labels;
    #pragma unroll
    for (int k = 0; k < M_SZ / 4 / 1024; ++k) {   // 16 iters
        int idx = k * 1024 + t;
        int4 l4 = L4[idx];
        int m0 = idx * 4;
        unsigned d;
        d = (unsigned)(l4.x - c0); if (d < CPB) list[d][atomicAdd(&lcur[d], 1)] = m0 + 0;
        d = (unsigned)(l4.y - c0); if (d < CPB) list[d][atomicAdd(&lcur[d], 1)] = m0 + 1;
        d = (unsigned)(l4.z - c0); if (d < CPB) list[d][atomicAdd(&lcur[d], 1)] = m0 + 2;
        d = (unsigned)(l4.w - c0); if (d < CPB) list[d][atomicAdd(&lcur[d], 1)] = m0 + 3;
    }
    __syncthreads();

    // ---- phase 2: float4 gather, 4 chains in flight ----
    int g = t >> 9;
    int tt = t & 511;
    int s = tt >> 6;
    int lane = tt & 63;
    int c = c0 + g;
    int n = lcur[g];
    const int* ml = list[g];
    float4 a = make_float4(0.f, 0.f, 0.f, 0.f);
    #pragma unroll 4
    for (int i = s; i < n; i += 8) {
        float4 v = *(const float4*)&features[(size_t)ml[i] * D_SZ + lane * 4];
        a.x += v.x; a.y += v.y; a.z += v.z; a.w += v.w;
    }
    red[g][s][lane] = a;
    __syncthreads();
    if (s == 0) {
        float4 z = make_float4(0.f, 0.f, 0.f, 0.f);
        #pragma unroll
        for (int q = 0; q < 8; ++q) {
            float4 r = red[g][q][lane];
            z.x += r.x; z.y += r.y; z.z += r.z; z.w += r.w;
        }
        float scale = 1.0f / (TEMP * (float)(n > 0 ? n : 1));
        ushort4 o;
        o.x = f2bf(z.x * scale); o.y = f2bf(z.y * scale);
        o.z = f2bf(z.z * scale); o.w = f2bf(z.w * scale);
        *(ushort4*)&fct[(size_t)lane * (C_SZ * 4) + c * 4] = o;
        if (lane == 0) nums[c] = n;
    }
}

// 256 blocks x 1024 thr, ONE row per block. bf16 fct (0.5MB per-block L2 pull
// — the R15 fp32 version doubled this and regressed). Thread t: dim-chunk
// q = t>>8 (64 dims), class-quad 4*(t&255). Per-thread ops halve vs R13.
__launch_bounds__(1024)
__global__ void k_loss(const float* __restrict__ feat,
                       const unsigned short* __restrict__ fct,
                       const int* __restrict__ nums,
                       const float* __restrict__ soft,
                       const int* __restrict__ indexes,
                       const int* __restrict__ labels,
                       const int* __restrict__ bil,
                       const int* __restrict__ cur_epoch,
                       float* __restrict__ acc, int* __restrict__ lcnt,
                       float* __restrict__ out) {
    __shared__ float xs[D_SZ];
    __shared__ float pa[4][256][5];   // [q][tt][cls], pad 5 -> no conflict
    __shared__ float wred[16], wred2[16];
    __shared__ float bc0;
    __shared__ int tgt0, sr0;

    int t = threadIdx.x;
    int lane = t & 63, wid = t >> 6;
    int r = blockIdx.x;

    if (t == 0) {
        tgt0 = labels[indexes[r]];
        sr0 = bil[r];
    }

    // ---- normalize row r ----
    float v = (t < D_SZ) ? feat[(size_t)r * D_SZ + t] : 0.f;
    float s = v * v;
    #pragma unroll
    for (int o = 32; o; o >>= 1) s += __shfl_down(s, o);
    if (lane == 0) wred[wid] = s;   // waves 0-3 hold the row
    __syncthreads();
    if (t == 0)
        bc0 = fmaxf(sqrtf(wred[0] + wred[1] + wred[2] + wred[3]), 1e-12f);
    __syncthreads();
    if (t < D_SZ) xs[t] = v / bc0;
    __syncthreads();

    // ---- phase B: partial sims for 4 classes over my 64 dims ----
    int q = t >> 8, tt = t & 255;
    int c0 = 4 * tt;
    float b0 = 0.f, b1 = 0.f, b2 = 0.f, b3 = 0.f;
    if (tt < 250) {
        int jb = q * 16;
        #pragma unroll 4
        for (int j = jb; j < jb + 16; ++j) {
            const unsigned short* base = fct + (size_t)j * (C_SZ * 4) + c0 * 4;
            int4 u0 = *(const int4*)base;        // cls c0, c0+1 (dims 4j..4j+3)
            int4 u1 = *(const int4*)(base + 8);  // cls c0+2, c0+3
            float4 x = *(const float4*)&xs[4 * j];   // ds_read_b128
            float f0, f1, f2, f3;
            f0 = BFLO(u0.x); f1 = BFHI(u0.x); f2 = BFLO(u0.y); f3 = BFHI(u0.y);
            b0 = fmaf(x.x, f0, b0); b0 = fmaf(x.y, f1, b0);
            b0 = fmaf(x.z, f2, b0); b0 = fmaf(x.w, f3, b0);
            f0 = BFLO(u0.z); f1 = BFHI(u0.z); f2 = BFLO(u0.w); f3 = BFHI(u0.w);
            b1 = fmaf(x.x, f0, b1); b1 = fmaf(x.y, f1, b1);
            b1 = fmaf(x.z, f2, b1); b1 = fmaf(x.w, f3, b1);
            f0 = BFLO(u1.x); f1 = BFHI(u1.x); f2 = BFLO(u1.y); f3 = BFHI(u1.y);
            b2 = fmaf(x.x, f0, b2); b2 = fmaf(x.y, f1, b2);
            b2 = fmaf(x.z, f2, b2); b2 = fmaf(x.w, f3, b2);
            f0 = BFLO(u1.z); f1 = BFHI(u1.z); f2 = BFLO(u1.w); f3 = BFHI(u1.w);
            b3 = fmaf(x.x, f0, b3); b3 = fmaf(x.y, f1, b3);
            b3 = fmaf(x.z, f2, b3); b3 = fmaf(x.w, f3, b3);
        }
    }
    pa[q][tt][0] = b0; pa[q][tt][1] = b1;
    pa[q][tt][2] = b2; pa[q][tt][3] = b3;
    __syncthreads();

    // ---- phase C: reduce partials, masked exp ----
    float e0[4] = {0.f, 0.f, 0.f, 0.f};
    float s0 = 0.f;
    if (t < 250) {
        int4 nm = *(const int4*)&nums[4 * t];
        #pragma unroll
        for (int k = 0; k < 4; ++k) {
            float a0 = (pa[0][t][k] + pa[1][t][k]) + (pa[2][t][k] + pa[3][t][k]);
            int nk = (k == 0) ? nm.x : (k == 1) ? nm.y : (k == 2) ? nm.z : nm.w;
            float mk = (nk > 0) ? 1.f : 0.f;
            e0[k] = mk * __expf(a0);
            s0 += e0[k];
        }
    }
    #pragma unroll
    for (int o = 32; o; o >>= 1) s0 += __shfl_down(s0, o);
    if (lane == 0) wred[wid] = s0;
    __syncthreads();
    if (t == 0) {
        float z0 = 0.f;
        #pragma unroll
        for (int i = 0; i < 16; ++i) z0 += wred[i];
        bc0 = z0;
    }
    __syncthreads();
    float inv0 = 1.0f / (bc0 + EPSF);

    // ---- loss partials ----
    float p1 = 0.f, p2 = 0.f;
    if (t < 250) {
        int c0b = 4 * t;
        float4 sp0 = *(const float4*)&soft[(size_t)sr0 * C_SZ + c0b];
        #pragma unroll
        for (int k = 0; k < 4; ++k) {
            float w0 = (k == 0) ? sp0.x : (k == 1) ? sp0.y : (k == 2) ? sp0.z : sp0.w;
            float lp0 = __logf(e0[k] * inv0 + EPSF);
            p2 -= w0 * lp0;
            if (c0b + k == tgt0) p1 -= lp0;
        }
    }
    #pragma unroll
    for (int o = 32; o; o >>= 1) {
        p1 += __shfl_down(p1, o);
        p2 += __shfl_down(p2, o);
    }
    __syncthreads();
    if (lane == 0) { wred[wid] = p1; wred2[wid] = p2; }
    __syncthreads();
    if (t == 0) {
        float z1 = 0.f, z2 = 0.f;
        #pragma unroll
        for (int i = 0; i < 16; ++i) { z1 += wred[i]; z2 += wred2[i]; }
        atomicAdd(&acc[0], z1);
        atomicAdd(&acc[1], z2);
        __threadfence();
        int done = atomicAdd(lcnt, 1);
        if (done == (int)gridDim.x - 1) {
            float l1 = atomicAdd(&acc[0], 0.f) / (float)B_SZ;
            float l2 = atomicAdd(&acc[1], 0.f) / (float)B_SZ;
            out[0] = (cur_epoch[0] == 0) ? l1 : 0.5f * (l1 + l2);
        }
    }
}

extern "C" void kernel_launch(void* const* d_in, const int* in_sizes, int n_in,
                              void* d_out, int out_size, void* d_ws, size_t ws_size,
                              hipStream_t stream) {
    const float* feat     = (const float*)d_in[0];
    const float* features = (const float*)d_in[1];
    const float* soft     = (const float*)d_in[2];
    const int* indexes    = (const int*)d_in[3];
    const int* labels     = (const int*)d_in[4];
    const int* bil        = (const int*)d_in[5];
    const int* cur_epoch  = (const int*)d_in[6];

    char* ws = (char*)d_ws;
    unsigned short* fct = (unsigned short*)(ws + OFF_FCT);
    int* nums    = (int*)(ws + OFF_NUMS);
    float* acc   = (float*)(ws + OFF_ACC);
    int* lcnt    = (int*)(ws + OFF_LCNT);

    k_csum<<<NBLK_CSUM, 1024, 0, stream>>>(features, labels, fct, nums, acc, lcnt);
    k_loss<<<B_SZ, 1024, 0, stream>>>(feat, fct, nums, soft, indexes, labels,
                                      bil, cur_epoch, acc, lcnt, (float*)d_out);
}

// Round 17
// 39.487 us; speedup vs baseline: 17.2765x; 1.1140x over previous
//
#include <hip/hip_runtime.h>
#include <hip/hip_bf16.h>

#define B_SZ 256
#define D_SZ 256
#define M_SZ 65536
#define C_SZ 1000
#define TEMP 0.05f
#define EPSF 1e-6f

#define CPB 4                    // classes per csum block (halves label-scan traffic)
#define NBLK_CSUM (C_SZ / CPB)   // 250 blocks
#define LCAP 512                 // member-list capacity (lambda=65.5)

// packed bf16 fct layout: ushort index (d>>2)*(C_SZ*4) + c*4 + (d&3)

// ---- ws layout (bytes) ----
#define OFF_FCT   0          // ushort[D_SZ*C_SZ] = 512,000 B (packed bf16)
#define OFF_NUMS  512000     // int[C_SZ]
#define OFF_ACC   516000     // float[2]
#define OFF_LCNT  516008     // int[1] loss ticket

static __device__ __forceinline__ unsigned short f2bf(float f) {
    __hip_bfloat16 h = __float2bfloat16(f);   // RNE
    return *reinterpret_cast<unsigned short*>(&h);
}
#define BFLO(u) __uint_as_float(((unsigned)(u)) << 16)
#define BFHI(u) __uint_as_float(((unsigned)(u)) & 0xffff0000u)

// Self-sufficient classsum: block b owns classes 4b..4b+3.
// Phase 1: scan all labels (int4, L2-broadcast) -> per-class LDS lists.
//          250 blocks x 256KB = 64MB L2 traffic (half of CPB=2).
// Phase 2: per class, 4 streams x 64 lanes; full 8-deep unroll -> 8 row
//          fetches in flight per stream (fairly testing R15's confounded
//          unroll bump). 4-way LDS tree reduce; packed bf16 write.
__launch_bounds__(1024)
__global__ void k_csum(const float* __restrict__ features,
                       const int* __restrict__ labels,
                       unsigned short* __restrict__ fct, int* __restrict__ nums,
                       float* __restrict__ acc, int* __restrict__ lcnt) {
    __shared__ int list[CPB][LCAP];
    __shared__ int lcur[CPB];
    __shared__ float4 red[CPB][4][64];   // 16 KB
    int t = threadIdx.x, b = blockIdx.x;
    int c0 = b * CPB;

    if (t < CPB) lcur[t] = 0;
    if (b == 0 && t == 0) { acc[0] = 0.f; acc[1] = 0.f; lcnt[0] = 0; }
    __syncthreads();

    // ---- phase 1: label scan ----
    const int4* L4 = (const int4*)labels;
    #pragma unroll
    for (int k = 0; k < M_SZ / 4 / 1024; ++k) {   // 16 iters
        int idx = k * 1024 + t;
        int4 l4 = L4[idx];
        int m0 = idx * 4;
        unsigned d;
        d = (unsigned)(l4.x - c0); if (d < CPB) list[d][atomicAdd(&lcur[d], 1)] = m0 + 0;
        d = (unsigned)(l4.y - c0); if (d < CPB) list[d][atomicAdd(&lcur[d], 1)] = m0 + 1;
        d = (unsigned)(l4.z - c0); if (d < CPB) list[d][atomicAdd(&lcur[d], 1)] = m0 + 2;
        d = (unsigned)(l4.w - c0); if (d < CPB) list[d][atomicAdd(&lcur[d], 1)] = m0 + 3;
    }
    __syncthreads();

    // ---- phase 2: float4 gather, 4 streams/class, 8 iters in flight ----
    int g = t >> 8;          // class subgroup 0..3
    int tt = t & 255;
    int s = tt >> 6;         // row stream 0..3
    int lane = tt & 63;      // 16B slice of the row
    int c = c0 + g;
    int n = lcur[g];
    const int* ml = list[g];
    float4 a = make_float4(0.f, 0.f, 0.f, 0.f);
    #pragma unroll 8
    for (int i = s; i < n; i += 4) {
        float4 v = *(const float4*)&features[(size_t)ml[i] * D_SZ + lane * 4];
        a.x += v.x; a.y += v.y; a.z += v.z; a.w += v.w;
    }
    red[g][s][lane] = a;
    __syncthreads();
    if (s == 0) {
        float4 z0 = red[g][0][lane], z1 = red[g][1][lane];
        float4 z2 = red[g][2][lane], z3 = red[g][3][lane];
        float zx = (z0.x + z1.x) + (z2.x + z3.x);
        float zy = (z0.y + z1.y) + (z2.y + z3.y);
        float zz = (z0.z + z1.z) + (z2.z + z3.z);
        float zw = (z0.w + z1.w) + (z2.w + z3.w);
        float scale = 1.0f / (TEMP * (float)(n > 0 ? n : 1));
        ushort4 o;
        o.x = f2bf(zx * scale); o.y = f2bf(zy * scale);
        o.z = f2bf(zz * scale); o.w = f2bf(zw * scale);
        *(ushort4*)&fct[(size_t)lane * (C_SZ * 4) + c * 4] = o;
        if (lane == 0) nums[c] = n;
    }
}

// EXACT R13 loss (best measured: 128 blocks x 2 rows, bf16 fct, dim-split).
__launch_bounds__(1024)
__global__ void k_loss(const float* __restrict__ feat,
                       const unsigned short* __restrict__ fct,
                       const int* __restrict__ nums,
                       const float* __restrict__ soft,
                       const int* __restrict__ indexes,
                       const int* __restrict__ labels,
                       const int* __restrict__ bil,
                       const int* __restrict__ cur_epoch,
                       float* __restrict__ acc, int* __restrict__ lcnt,
                       float* __restrict__ out) {
    __shared__ float xs0[D_SZ], xs1[D_SZ];
    __shared__ float pa[4][256][9];   // [q][tt][cls*2+row], pad 9
    __shared__ float wred[16], wred2[16];
    __shared__ float bc0, bc1;
    __shared__ int tgt0, tgt1, sr0, sr1;

    int t = threadIdx.x;
    int lane = t & 63, wid = t >> 6;
    int r0 = blockIdx.x * 2;

    if (t == 0) {
        tgt0 = labels[indexes[r0]];
        tgt1 = labels[indexes[r0 + 1]];
        sr0 = bil[r0];
        sr1 = bil[r0 + 1];
    }

    // ---- normalize rows 2r,2r+1 (contiguous 512 floats) ----
    float v = (t < 512) ? feat[(size_t)r0 * D_SZ + t] : 0.f;
    float s = v * v;
    #pragma unroll
    for (int o = 32; o; o >>= 1) s += __shfl_down(s, o);
    if (lane == 0) wred[wid] = s;  // waves 0-3 = row0, 4-7 = row1
    __syncthreads();
    if (t == 0) {
        bc0 = fmaxf(sqrtf(wred[0] + wred[1] + wred[2] + wred[3]), 1e-12f);
        bc1 = fmaxf(sqrtf(wred[4] + wred[5] + wred[6] + wred[7]), 1e-12f);
    }
    __syncthreads();
    if (t < 256) xs0[t] = v / bc0;
    else if (t < 512) xs1[t - 256] = v / bc1;
    __syncthreads();

    // ---- phase B: partial sims for 4 classes x 2 rows over my 64 dims ----
    int q = t >> 8, tt = t & 255;
    int c0 = 4 * tt;
    float b00 = 0.f, b01 = 0.f, b02 = 0.f, b03 = 0.f;
    float b10 = 0.f, b11 = 0.f, b12 = 0.f, b13 = 0.f;
    if (tt < 250) {
        int jb = q * 16;
        #pragma unroll 4
        for (int j = jb; j < jb + 16; ++j) {
            const unsigned short* base = fct + (size_t)j * (C_SZ * 4) + c0 * 4;
            int4 u0 = *(const int4*)base;
            int4 u1 = *(const int4*)(base + 8);
            float4 x0 = *(const float4*)&xs0[4 * j];
            float4 x1 = *(const float4*)&xs1[4 * j];
            float f0, f1, f2, f3;
            f0 = BFLO(u0.x); f1 = BFHI(u0.x); f2 = BFLO(u0.y); f3 = BFHI(u0.y);
            b00 = fmaf(x0.x, f0, b00); b00 = fmaf(x0.y, f1, b00);
            b00 = fmaf(x0.z, f2, b00); b00 = fmaf(x0.w, f3, b00);
            b10 = fmaf(x1.x, f0, b10); b10 = fmaf(x1.y, f1, b10);
            b10 = fmaf(x1.z, f2, b10); b10 = fmaf(x1.w, f3, b10);
            f0 = BFLO(u0.z); f1 = BFHI(u0.z); f2 = BFLO(u0.w); f3 = BFHI(u0.w);
            b01 = fmaf(x0.x, f0, b01); b01 = fmaf(x0.y, f1, b01);
            b01 = fmaf(x0.z, f2, b01); b01 = fmaf(x0.w, f3, b01);
            b11 = fmaf(x1.x, f0, b11); b11 = fmaf(x1.y, f1, b11);
            b11 = fmaf(x1.z, f2, b11); b11 = fmaf(x1.w, f3, b11);
            f0 = BFLO(u1.x); f1 = BFHI(u1.x); f2 = BFLO(u1.y); f3 = BFHI(u1.y);
            b02 = fmaf(x0.x, f0, b02); b02 = fmaf(x0.y, f1, b02);
            b02 = fmaf(x0.z, f2, b02); b02 = fmaf(x0.w, f3, b02);
            b12 = fmaf(x1.x, f0, b12); b12 = fmaf(x1.y, f1, b12);
            b12 = fmaf(x1.z, f2, b12); b12 = fmaf(x1.w, f3, b12);
            f0 = BFLO(u1.z); f1 = BFHI(u1.z); f2 = BFLO(u1.w); f3 = BFHI(u1.w);
            b03 = fmaf(x0.x, f0, b03); b03 = fmaf(x0.y, f1, b03);
            b03 = fmaf(x0.z, f2, b03); b03 = fmaf(x0.w, f3, b03);
            b13 = fmaf(x1.x, f0, b13); b13 = fmaf(x1.y, f1, b13);
            b13 = fmaf(x1.z, f2, b13); b13 = fmaf(x1.w, f3, b13);
        }
    }
    pa[q][tt][0] = b00; pa[q][tt][1] = b10;
    pa[q][tt][2] = b01; pa[q][tt][3] = b11;
    pa[q][tt][4] = b02; pa[q][tt][5] = b12;
    pa[q][tt][6] = b03; pa[q][tt][7] = b13;
    __syncthreads();

    // ---- phase C: reduce partials, masked exp ----
    float e0[4] = {0.f, 0.f, 0.f, 0.f};
    float e1[4] = {0.f, 0.f, 0.f, 0.f};
    float s0 = 0.f, s1 = 0.f;
    if (t < 250) {
        int4 nm = *(const int4*)&nums[4 * t];
        #pragma unroll
        for (int k = 0; k < 4; ++k) {
            float a0 = (pa[0][t][2 * k] + pa[1][t][2 * k]) +
                       (pa[2][t][2 * k] + pa[3][t][2 * k]);
            float a1 = (pa[0][t][2 * k + 1] + pa[1][t][2 * k + 1]) +
                       (pa[2][t][2 * k + 1] + pa[3][t][2 * k + 1]);
            int nk = (k == 0) ? nm.x : (k == 1) ? nm.y : (k == 2) ? nm.z : nm.w;
            float mk = (nk > 0) ? 1.f : 0.f;
            e0[k] = mk * __expf(a0);
            e1[k] = mk * __expf(a1);
            s0 += e0[k];
            s1 += e1[k];
        }
    }
    #pragma unroll
    for (int o = 32; o; o >>= 1) {
        s0 += __shfl_down(s0, o);
        s1 += __shfl_down(s1, o);
    }
    if (lane == 0) { wred[wid] = s0; wred2[wid] = s1; }
    __syncthreads();
    if (t == 0) {
        float z0 = 0.f, z1 = 0.f;
        #pragma unroll
        for (int i = 0; i < 16; ++i) { z0 += wred[i]; z1 += wred2[i]; }
        bc0 = z0; bc1 = z1;
    }
    __syncthreads();
    float inv0 = 1.0f / (bc0 + EPSF);
    float inv1 = 1.0f / (bc1 + EPSF);

    // ---- loss partials ----
    float p1 = 0.f, p2 = 0.f;
    if (t < 250) {
        int c0b = 4 * t;
        float4 sp0 = *(const float4*)&soft[(size_t)sr0 * C_SZ + c0b];
        float4 sp1 = *(const float4*)&soft[(size_t)sr1 * C_SZ + c0b];
        #pragma unroll
        for (int k = 0; k < 4; ++k) {
            float w0 = (k == 0) ? sp0.x : (k == 1) ? sp0.y : (k == 2) ? sp0.z : sp0.w;
            float w1 = (k == 0) ? sp1.x : (k == 1) ? sp1.y : (k == 2) ? sp1.z : sp1.w;
            float lp0 = __logf(e0[k] * inv0 + EPSF);
            float lp1 = __logf(e1[k] * inv1 + EPSF);
            p2 -= w0 * lp0 + w1 * lp1;
            if (c0b + k == tgt0) p1 -= lp0;
            if (c0b + k == tgt1) p1 -= lp1;
        }
    }
    #pragma unroll
    for (int o = 32; o; o >>= 1) {
        p1 += __shfl_down(p1, o);
        p2 += __shfl_down(p2, o);
    }
    __syncthreads();
    if (lane == 0) { wred[wid] = p1; wred2[wid] = p2; }
    __syncthreads();
    if (t == 0) {
        float z1 = 0.f, z2 = 0.f;
        #pragma unroll
        for (int i = 0; i < 16; ++i) { z1 += wred[i]; z2 += wred2[i]; }
        atomicAdd(&acc[0], z1);
        atomicAdd(&acc[1], z2);
        __threadfence();
        int done = atomicAdd(lcnt, 1);
        if (done == (int)gridDim.x - 1) {
            float l1 = atomicAdd(&acc[0], 0.f) / (float)B_SZ;
            float l2 = atomicAdd(&acc[1], 0.f) / (float)B_SZ;
            out[0] = (cur_epoch[0] == 0) ? l1 : 0.5f * (l1 + l2);
        }
    }
}

extern "C" void kernel_launch(void* const* d_in, const int* in_sizes, int n_in,
                              void* d_out, int out_size, void* d_ws, size_t ws_size,
                              hipStream_t stream) {
    const float* feat     = (const float*)d_in[0];
    const float* features = (const float*)d_in[1];
    const float* soft     = (const float*)d_in[2];
    const int* indexes    = (const int*)d_in[3];
    const int* labels     = (const int*)d_in[4];
    const int* bil        = (const int*)d_in[5];
    const int* cur_epoch  = (const int*)d_in[6];

    char* ws = (char*)d_ws;
    unsigned short* fct = (unsigned short*)(ws + OFF_FCT);
    int* nums    = (int*)(ws + OFF_NUMS);
    float* acc   = (float*)(ws + OFF_ACC);
    int* lcnt    = (int*)(ws + OFF_LCNT);

    k_csum<<<NBLK_CSUM, 1024, 0, stream>>>(features, labels, fct, nums, acc, lcnt);
    k_loss<<<B_SZ / 2, 1024, 0, stream>>>(feat, fct, nums, soft, indexes, labels,
                                          bil, cur_epoch, acc, lcnt, (float*)d_out);
}